// Round 5
// baseline (5297.684 us; speedup 1.0000x reference)
//
#include <hip/hip_runtime.h>
#include <cstdint>
#include <cstddef>

// Problem dims (fixed by setup_inputs)
#define BB    2048
#define SS    256
#define HH    256
#define AA    2
#define TT    50
#define NB    8      // batch rows per block
#define NBLK  256    // one block per CU
#define NTHR  1024   // 16 waves/block -> 4 waves/SIMD
#define NJ    2      // batch rows per thread

struct Params {
  const float* x;
  const float* fu[3]; const float* fv[3]; const float* fs[3];
  const float* f4u; const float* f4v; const float* f4s;
  const float* W[3]; const float* bs[3];
  const float* W4; const float* b4;
  float* out;
  float* partials;    // [2 slots][4 layers][6 stats][NBLK]
  unsigned* bar;      // [ctr, gen] (monotone)
  float* xT;          // [TT][BB*SS] (optional)
  int use_xt;
};

__device__ __forceinline__ void pstore(float* p, float v) {
  __hip_atomic_store(p, v, __ATOMIC_RELAXED, __HIP_MEMORY_SCOPE_AGENT);
}
__device__ __forceinline__ float pload(const float* p) {
  return __hip_atomic_load(p, __ATOMIC_RELAXED, __HIP_MEMORY_SCOPE_AGENT);
}

// Split grid barrier (monotone). All 256 blocks co-resident (1/CU).
__device__ __forceinline__ void bar_arrive(unsigned* bar, int b) {
  __syncthreads();
  if (threadIdx.x == 0) {
    unsigned old = __hip_atomic_fetch_add(bar, 1u, __ATOMIC_ACQ_REL, __HIP_MEMORY_SCOPE_AGENT);
    if (old == (unsigned)((b + 1) * NBLK - 1))
      __hip_atomic_store(bar + 1, (unsigned)(b + 1), __ATOMIC_RELEASE, __HIP_MEMORY_SCOPE_AGENT);
  }
}
__device__ __forceinline__ void bar_wait(unsigned* bar, int b) {
  if (threadIdx.x == 0) {
    while ((int)__hip_atomic_load(bar + 1, __ATOMIC_ACQUIRE, __HIP_MEMORY_SCOPE_AGENT) < b + 1)
      __builtin_amdgcn_s_sleep(2);
  }
  __syncthreads();
}

__global__ __launch_bounds__(NTHR)
void snn_kernel(Params p) {
#pragma clang fp contract(off)
  const int tid  = threadIdx.x;
  const int blk  = blockIdx.x;
  const int gtid = blk * NTHR + tid;
  const int B0   = blk * NB;

  const int h0 = tid & 255;        // hidden index / s index
  const int jg = tid >> 8;         // 0..3  (j-group)
  const int j0 = jg * NJ;          // block-local batch row of cell 0

  __shared__ __align__(16) float in_lds[NB * 256];   // [j][k] input / spikes
  __shared__ float wred[16][6];
  __shared__ float scal[4][2];
  __shared__ float l4u[16], l4v[16], l4s[16], l4t[16], l4acc[16], l4vn[16], l4vth[16];

  // ---- prologue: transpose x -> xT[t][b*SS+s] ----
  if (p.use_xt) {
    #pragma unroll
    for (int q = 0; q < 2; ++q) {
      int sid = gtid + q * (NBLK * NTHR);
      const float* src = p.x + (size_t)sid * TT;
      for (int t = 0; t < TT; ++t)
        p.xT[(size_t)t * (BB * SS) + sid] = src[t];
    }
  }

  // ---- recurrent state: 3 layers x 2 cells ----
  float u[3][NJ], v[3][NJ], s[3][NJ], tp[3][NJ];
  #pragma unroll
  for (int l = 0; l < 3; ++l)
    #pragma unroll
    for (int jj = 0; jj < NJ; ++jj) {
      size_t idx = (size_t)(B0 + j0 + jj) * HH + h0;
      u[l][jj] = p.fu[l][idx];
      v[l][jj] = p.fv[l][idx];
      s[l][jj] = p.fs[l][idx];
      tp[l][jj] = 0.5f;
    }
  if (tid < 16) {
    int j = tid >> 1, a = tid & 1;
    size_t idx = (size_t)(B0 + j) * AA + a;
    l4u[tid] = p.f4u[idx]; l4v[tid] = p.f4v[idx]; l4s[tid] = p.f4s[idx];
    l4t[tid] = 0.5f; l4acc[tid] = 0.0f;
  }
  const float bL[3] = { p.bs[0][h0], p.bs[1][h0], p.bs[2][h0] };

  bar_arrive(p.bar, 0);
  bar_wait(p.bar, 0);   // xT visible; also covers LDS init

  auto load_xt = [&](int t) {
    #pragma unroll
    for (int jj = 0; jj < NJ; ++jj) {
      int j = j0 + jj;
      if (p.use_xt)
        in_lds[j * 256 + h0] = p.xT[(size_t)t * (BB * SS) + (size_t)(B0 + j) * SS + h0];
      else
        in_lds[j * 256 + h0] = p.x[((size_t)(B0 + j) * SS + h0) * TT + t];
    }
  };

  // GEMM: acc[jj] = sum_k W[h0][k] * in[j0+jj][k], ascending k (bit-exact chain)
  auto gemm = [&](const float* __restrict__ wrow, float acc[NJ]) {
    acc[0] = acc[1] = 0.0f;
    const float* r0 = &in_lds[j0 * 256];
    const float* r1 = &in_lds[(j0 + 1) * 256];
    #pragma unroll 4
    for (int k4 = 0; k4 < 64; ++k4) {
      float4 w = *reinterpret_cast<const float4*>(wrow + k4 * 4);
      float4 a = *reinterpret_cast<const float4*>(r0 + k4 * 4);
      float4 b = *reinterpret_cast<const float4*>(r1 + k4 * 4);
      acc[0] = fmaf(a.x, w.x, acc[0]); acc[0] = fmaf(a.y, w.y, acc[0]);
      acc[0] = fmaf(a.z, w.z, acc[0]); acc[0] = fmaf(a.w, w.w, acc[0]);
      acc[1] = fmaf(b.x, w.x, acc[1]); acc[1] = fmaf(b.y, w.y, acc[1]);
      acc[1] = fmaf(b.z, w.z, acc[1]); acc[1] = fmaf(b.w, w.w, acc[1]);
    }
  };

  // LIF + stats + spike publish for layers 0..2
  auto lif_layer = [&](int l, float acc[NJ], int t) {
    const float bbx = bL[l];
    float sv = 0.f, svt = 0.f;
    float mxv = -3.402823466e38f, mnv = 3.402823466e38f;
    float mxvt = -3.402823466e38f, mnvt = 3.402823466e38f;
    float sn[NJ];
    #pragma unroll
    for (int jj = 0; jj < NJ; ++jj) {
      float un = fmaf(u[l][jj], 0.5f, acc[jj]) + bbx;
      float vp = v[l][jj];
      float vd = (vp * 0.75f) * (1.0f - s[l][jj]);
      float vn = vd + un;
      float en = expf((vp - vn) / 3.0f) - 1.0f;
      float vt = 0.5f * tp[l][jj] + 0.5f * en;
      float sx = (vn > vt) ? 1.0f : 0.0f;
      u[l][jj] = un; v[l][jj] = vn; s[l][jj] = sx;
      sn[jj] = sx;
      sv += vn; svt += vt;
      mxv = fmaxf(mxv, vn); mnv = fminf(mnv, vn);
      mxvt = fmaxf(mxvt, vt); mnvt = fminf(mnvt, vt);
    }
    #pragma unroll
    for (int m = 1; m < 64; m <<= 1) {
      sv += __shfl_xor(sv, m);   svt += __shfl_xor(svt, m);
      mxv = fmaxf(mxv, __shfl_xor(mxv, m));  mnv = fminf(mnv, __shfl_xor(mnv, m));
      mxvt = fmaxf(mxvt, __shfl_xor(mxvt, m)); mnvt = fminf(mnvt, __shfl_xor(mnvt, m));
    }
    __syncthreads();   // all GEMM reads of in_lds done; wred slot free
    if ((tid & 63) == 0) {
      int wv = tid >> 6;
      wred[wv][0] = sv;  wred[wv][1] = mxv;  wred[wv][2] = mnv;
      wred[wv][3] = svt; wred[wv][4] = mxvt; wred[wv][5] = mnvt;
    }
    in_lds[j0 * 256 + h0] = sn[0];
    in_lds[(j0 + 1) * 256 + h0] = sn[1];
    __syncthreads();   // spikes + wred visible
    if (tid < 6) {
      int st = tid;
      float r;
      if (st == 0 || st == 3) {
        r = wred[0][st];
        #pragma unroll
        for (int wv = 1; wv < 16; ++wv) r = r + wred[wv][st];
      } else if (st == 1 || st == 4) {
        r = wred[0][st];
        #pragma unroll
        for (int wv = 1; wv < 16; ++wv) r = fmaxf(r, wred[wv][st]);
      } else {
        r = wred[0][st];
        #pragma unroll
        for (int wv = 1; wv < 16; ++wv) r = fminf(r, wred[wv][st]);
      }
      pstore(&p.partials[(((size_t)(t & 1) * 4 + l) * 6 + st) * NBLK + blk], r);
    }
  };

  #pragma unroll 1
  for (int t = 0; t < TT; ++t) {
    load_xt(t);
    __syncthreads();

    // ---- layer 1 GEMM (stats barrier hides behind it) ----
    float acc[NJ];
    gemm(p.W[0] + (size_t)h0 * SS, acc);

    if (t > 0) {
      bar_wait(p.bar, t);
      {
        const int wv = tid >> 6, ln = tid & 63;
        if (wv < 4) {
          const float* pb = p.partials + ((size_t)((t - 1) & 1) * 4 + wv) * 6 * NBLK;
          float r[6];
          #pragma unroll
          for (int st = 0; st < 6; ++st) {
            const float* q = pb + st * NBLK;
            float a0 = pload(q + ln),       a1 = pload(q + ln + 64);
            float a2 = pload(q + ln + 128), a3 = pload(q + ln + 192);
            float rr;
            if (st == 0 || st == 3) {
              rr = ((a0 + a1) + a2) + a3;
              #pragma unroll
              for (int m = 1; m < 64; m <<= 1) rr += __shfl_xor(rr, m);
            } else if (st == 1 || st == 4) {
              rr = fmaxf(fmaxf(a0, a1), fmaxf(a2, a3));
              #pragma unroll
              for (int m = 1; m < 64; m <<= 1) rr = fmaxf(rr, __shfl_xor(rr, m));
            } else {
              rr = fminf(fminf(a0, a1), fminf(a2, a3));
              #pragma unroll
              for (int m = 1; m < 64; m <<= 1) rr = fminf(rr, __shfl_xor(rr, m));
            }
            r[st] = rr;
          }
          if (ln == 0) {
            const float invN = (wv == 3) ? (1.0f / 4096.0f) : (1.0f / 524288.0f);
            scal[wv][0] = (r[0] * invN) - 0.2f * (r[1] - r[2]);
            scal[wv][1] = (r[3] * invN) - 0.2f * (r[4] - r[5]);
          }
        }
      }
      __syncthreads();
      #pragma unroll
      for (int l2 = 0; l2 < 3; ++l2) {
        const float Vm = scal[l2][0], Vt = scal[l2][1];
        #pragma unroll
        for (int jj = 0; jj < NJ; ++jj) {
          float d = v[l2][jj] - Vm;   // v holds v(t-1)
          float sp = logf(1.0f + expf(d * 0.25f));
          tp[l2][jj] = (0.01f * d + Vt) + sp;
        }
      }
      if (tid < 16) {
        const float Vm = scal[3][0], Vt = scal[3][1];
        float d = l4v[tid] - Vm;
        float sp = logf(1.0f + expf(d * 0.25f));
        l4t[tid] = (0.01f * d + Vt) + sp;
      }
      __syncthreads();
    }

    lif_layer(0, acc, t);

    gemm(p.W[1] + (size_t)h0 * HH, acc);
    lif_layer(1, acc, t);
    gemm(p.W[2] + (size_t)h0 * HH, acc);
    lif_layer(2, acc, t);

    // ---- layer 4 (H -> 2), same tree as rounds 1-4 ----
    {
      const int g = tid >> 4, c = tid & 15;
      if (g < 16) {
        const int j4 = g >> 1, a4 = g & 1;
        float part = 0.0f;
        #pragma unroll
        for (int i = 0; i < 16; ++i) {
          int k = c + 16 * i;
          part = fmaf(in_lds[j4 * 256 + k], p.W4[a4 * HH + k], part);
        }
        #pragma unroll
        for (int m = 1; m < 16; m <<= 1) part += __shfl_xor(part, m);
        if (c == 0) {
          float un = fmaf(l4u[g], 0.5f, part) + p.b4[a4];
          float vp = l4v[g];
          float vd = (vp * 0.75f) * (1.0f - l4s[g]);
          float vn = vd + un;
          float en = expf((vp - vn) / 3.0f) - 1.0f;
          float vt = 0.5f * l4t[g] + 0.5f * en;
          float sx = (vn > vt) ? 1.0f : 0.0f;
          l4u[g] = un; l4v[g] = vn; l4s[g] = sx;
          l4acc[g] += sx; l4vn[g] = vn; l4vth[g] = vt;
        }
      }
    }
    __syncthreads();

    if (tid == 0) {
      float sv4 = l4vn[0], mx4 = l4vn[0], mn4 = l4vn[0];
      float st4 = l4vth[0], mxt4 = l4vth[0], mnt4 = l4vth[0];
      #pragma unroll
      for (int g2 = 1; g2 < 16; ++g2) {
        sv4 += l4vn[g2]; mx4 = fmaxf(mx4, l4vn[g2]); mn4 = fminf(mn4, l4vn[g2]);
        st4 += l4vth[g2]; mxt4 = fmaxf(mxt4, l4vth[g2]); mnt4 = fminf(mnt4, l4vth[g2]);
      }
      float* pp = p.partials + ((size_t)(t & 1) * 4 + 3) * 6 * NBLK + blk;
      pstore(pp + 0 * NBLK, sv4);  pstore(pp + 1 * NBLK, mx4);  pstore(pp + 2 * NBLK, mn4);
      pstore(pp + 3 * NBLK, st4);  pstore(pp + 4 * NBLK, mxt4); pstore(pp + 5 * NBLK, mnt4);
    }

    if (t < TT - 1) bar_arrive(p.bar, t + 1);
  }

  __syncthreads();
  if (tid < 16) {
    int j = tid >> 1, a = tid & 1;
    p.out[(size_t)(B0 + j) * AA + a] = l4acc[tid] / 50.0f;
  }
}

extern "C" void kernel_launch(void* const* d_in, const int* in_sizes, int n_in,
                              void* d_out, int out_size, void* d_ws, size_t ws_size,
                              hipStream_t stream) {
  Params p;
  p.x     = (const float*)d_in[0];
  p.fu[0] = (const float*)d_in[1];  p.fv[0] = (const float*)d_in[2];  p.fs[0] = (const float*)d_in[3];
  p.fu[1] = (const float*)d_in[4];  p.fv[1] = (const float*)d_in[5];  p.fs[1] = (const float*)d_in[6];
  p.fu[2] = (const float*)d_in[7];  p.fv[2] = (const float*)d_in[8];  p.fs[2] = (const float*)d_in[9];
  p.f4u   = (const float*)d_in[10]; p.f4v   = (const float*)d_in[11]; p.f4s   = (const float*)d_in[12];
  p.W[0]  = (const float*)d_in[13]; p.bs[0] = (const float*)d_in[14];
  p.W[1]  = (const float*)d_in[15]; p.bs[1] = (const float*)d_in[16];
  p.W[2]  = (const float*)d_in[17]; p.bs[2] = (const float*)d_in[18];
  p.W4    = (const float*)d_in[19]; p.b4    = (const float*)d_in[20];
  p.out   = (float*)d_out;

  float* ws  = (float*)d_ws;
  p.partials = ws;                        // 2*4*6*256 = 12288 floats
  p.bar      = (unsigned*)(ws + 12288);   // 2 uints (pad to 64)
  p.xT       = ws + 12352;                // 50*524288 floats (optional)
  size_t need = ((size_t)12352 + (size_t)TT * BB * SS) * sizeof(float);
  p.use_xt   = (ws_size >= need) ? 1 : 0;

  hipMemsetAsync((void*)p.bar, 0, 2 * sizeof(unsigned), stream);
  snn_kernel<<<dim3(NBLK), dim3(NTHR), 0, stream>>>(p);
}

// Round 7
// 3436.949 us; speedup vs baseline: 1.5414x; 1.5414x over previous
//
#include <hip/hip_runtime.h>
#include <cstdint>
#include <cstddef>

// Problem dims (fixed by setup_inputs)
#define BB    2048
#define SS    256
#define HH    256
#define AA    2
#define TT    50
#define NB    4      // batch rows per block
#define NBLK  512    // blocks -> 2 per CU
#define NTHR  256
#define K4PAD 1088           // floats per k4 tile (4352B stride: coalesced AND no L1 set aliasing)
#define WLAYER (64 * K4PAD)  // 69632 floats per layer

struct Params {
  const float* x;
  const float* fu[3]; const float* fv[3]; const float* fs[3];
  const float* f4u; const float* f4v; const float* f4s;
  const float* W[3]; const float* bs[3];
  const float* W4; const float* b4;
  float* out;
  float* wt3;         // [3][64 k4][256 h][4] padded
  float* partials;    // [2 slots][4 layers][6 stats][NBLK]
  unsigned* bar;      // [ctr, gen] (monotone)
  float* xT;          // [TT][BB*SS] (optional)
  int use_xt;
};

__device__ __forceinline__ void pstore(float* p, float v) {
  __hip_atomic_store(p, v, __ATOMIC_RELAXED, __HIP_MEMORY_SCOPE_AGENT);
}
__device__ __forceinline__ float pload(const float* p) {
  return __hip_atomic_load(p, __ATOMIC_RELAXED, __HIP_MEMORY_SCOPE_AGENT);
}

// Split grid barrier (monotone). All NBLK=512 blocks co-resident (2/CU).
__device__ __forceinline__ void bar_arrive(unsigned* bar, int b) {
  __syncthreads();
  if (threadIdx.x == 0) {
    unsigned old = __hip_atomic_fetch_add(bar, 1u, __ATOMIC_ACQ_REL, __HIP_MEMORY_SCOPE_AGENT);
    if (old == (unsigned)((b + 1) * NBLK - 1))
      __hip_atomic_store(bar + 1, (unsigned)(b + 1), __ATOMIC_RELEASE, __HIP_MEMORY_SCOPE_AGENT);
  }
}
__device__ __forceinline__ void bar_wait(unsigned* bar, int b) {
  if (threadIdx.x == 0) {
    while ((int)__hip_atomic_load(bar + 1, __ATOMIC_ACQUIRE, __HIP_MEMORY_SCOPE_AGENT) < b + 1)
      __builtin_amdgcn_s_sleep(2);
  }
  __syncthreads();
}

#define FMA4(ACC, IV, WS)                 \
  ACC[0] = fmaf((IV).x, (WS), ACC[0]);    \
  ACC[1] = fmaf((IV).y, (WS), ACC[1]);    \
  ACC[2] = fmaf((IV).z, (WS), ACC[2]);    \
  ACC[3] = fmaf((IV).w, (WS), ACC[3]);

__global__ __launch_bounds__(NTHR, 2)
void snn_kernel(Params p) {
#pragma clang fp contract(off)
  const int tid  = threadIdx.x;
  const int blk  = blockIdx.x;
  const int gtid = blk * NTHR + tid;
  const int B0   = blk * NB;
  const int h0   = tid;

  __shared__ __align__(16) float in_lds[HH * NB];   // [k][j] input / spikes
  __shared__ float wred[4][6];
  __shared__ float scal[4][2];
  __shared__ float l4u[8], l4v[8], l4s[8], l4t[8], l4acc[8], l4vn[8], l4vth[8];

  // ---- prologue 1: W -> padded coalesced k-tiles (blocks 0..63) ----
  if (gtid < 16384) {
    const int h = tid, k4 = blk;   // blk < 64
    #pragma unroll
    for (int l = 0; l < 3; ++l) {
      float4 w = *reinterpret_cast<const float4*>(p.W[l] + (size_t)h * 256 + k4 * 4);
      *reinterpret_cast<float4*>(p.wt3 + (size_t)l * WLAYER + (size_t)k4 * K4PAD + h * 4) = w;
    }
  }
  // ---- prologue 2: transpose x -> xT[t][b*SS+s] ----
  if (p.use_xt) {
    for (int q = 0; q < 4; ++q) {
      int sid = gtid + q * (NBLK * NTHR);
      const float* src = p.x + (size_t)sid * TT;
      for (int t = 0; t < TT; ++t)
        p.xT[(size_t)t * (BB * SS) + sid] = src[t];
    }
  }

  // ---- recurrent state ----
  float u[3][NB], v[3][NB], s[3][NB], tp[3][NB];
  #pragma unroll
  for (int l = 0; l < 3; ++l)
    #pragma unroll
    for (int j = 0; j < NB; ++j) {
      size_t idx = (size_t)(B0 + j) * HH + h0;
      u[l][j]  = p.fu[l][idx];
      v[l][j]  = p.fv[l][idx];
      s[l][j]  = p.fs[l][idx];
      tp[l][j] = 0.5f;
    }
  if (tid < 8) {
    int j = tid >> 1, a = tid & 1;
    size_t idx = (size_t)(B0 + j) * AA + a;
    l4u[tid] = p.f4u[idx]; l4v[tid] = p.f4v[idx]; l4s[tid] = p.f4s[idx];
    l4t[tid] = 0.5f; l4acc[tid] = 0.0f;
  }
  const float bL[3] = { p.bs[0][h0], p.bs[1][h0], p.bs[2][h0] };

  bar_arrive(p.bar, 0);
  bar_wait(p.bar, 0);   // wt3 + xT visible; also covers LDS init

  auto load_xt = [&](int t) {
    if (p.use_xt) {
      const float* base = p.xT + (size_t)t * (BB * SS) + (size_t)blk * NB * SS;
      float4 vv = make_float4(base[tid], base[SS + tid],
                              base[2 * SS + tid], base[3 * SS + tid]);
      *reinterpret_cast<float4*>(&in_lds[tid * NB]) = vv;
    } else {
      float4 vv = make_float4(
          p.x[((size_t)(B0 + 0) * SS + tid) * TT + t],
          p.x[((size_t)(B0 + 1) * SS + tid) * TT + t],
          p.x[((size_t)(B0 + 2) * SS + tid) * TT + t],
          p.x[((size_t)(B0 + 3) * SS + tid) * TT + t]);
      *reinterpret_cast<float4*>(&in_lds[tid * NB]) = vv;
    }
  };

  // GEMM: acc[j] += sum_k wt3[k][h0] * in[k][j], ascending k, 4-deep W prefetch.
  // Per-accumulator fmaf chain bit-identical to rounds 1-5.
  auto gemm = [&](const float* __restrict__ wb, float acc[NB]) {
    acc[0] = acc[1] = acc[2] = acc[3] = 0.0f;
    const float* wpf = wb + (h0 << 2);
    float4 w0 = *reinterpret_cast<const float4*>(wpf + 0 * K4PAD);
    float4 w1 = *reinterpret_cast<const float4*>(wpf + 1 * K4PAD);
    float4 w2 = *reinterpret_cast<const float4*>(wpf + 2 * K4PAD);
    float4 w3 = *reinterpret_cast<const float4*>(wpf + 3 * K4PAD);
    #pragma unroll 1
    for (int k4 = 0; k4 < 64; k4 += 4) {
      const int nk = (k4 + 4 < 64) ? (k4 + 4) : 0;   // dummy re-read on last iter
      float4 n0 = *reinterpret_cast<const float4*>(wpf + (nk + 0) * K4PAD);
      float4 n1 = *reinterpret_cast<const float4*>(wpf + (nk + 1) * K4PAD);
      float4 n2 = *reinterpret_cast<const float4*>(wpf + (nk + 2) * K4PAD);
      float4 n3 = *reinterpret_cast<const float4*>(wpf + (nk + 3) * K4PAD);
      #pragma unroll
      for (int q = 0; q < 4; ++q) {
        const float4 w = (q == 0) ? w0 : (q == 1) ? w1 : (q == 2) ? w2 : w3;
        const float* srow = &in_lds[(size_t)(k4 + q) * 4 * NB];
        float4 i0 = *reinterpret_cast<const float4*>(srow + 0);
        float4 i1 = *reinterpret_cast<const float4*>(srow + 4);
        float4 i2 = *reinterpret_cast<const float4*>(srow + 8);
        float4 i3 = *reinterpret_cast<const float4*>(srow + 12);
        FMA4(acc, i0, w.x);
        FMA4(acc, i1, w.y);
        FMA4(acc, i2, w.z);
        FMA4(acc, i3, w.w);
      }
      w0 = n0; w1 = n1; w2 = n2; w3 = n3;
    }
  };

  load_xt(0);   // <-- the round-6 bug: this call was missing

  #pragma unroll 1
  for (int t = 0; t < TT; ++t) {
    __syncthreads();   // in_lds (x_t) ready

    // ---------------- layers 1..3 ----------------
    #pragma unroll
    for (int l = 0; l < 3; ++l) {
      float acc[NB];
      gemm(p.wt3 + (size_t)l * WLAYER, acc);

      if (l == 0 && t > 0) {
        // stats barrier for step t-1 — hidden behind the layer-1 GEMM above
        bar_wait(p.bar, t);
        {
          const int wv = tid >> 6, ln = tid & 63;
          const float* pb = p.partials + ((size_t)((t - 1) & 1) * 4 + wv) * 6 * NBLK;
          float r[6];
          #pragma unroll
          for (int st = 0; st < 6; ++st) {
            const float* q = pb + st * NBLK;
            float a0 = pload(q + ln),       a1 = pload(q + ln + 64);
            float a2 = pload(q + ln + 128), a3 = pload(q + ln + 192);
            float a4 = pload(q + ln + 256), a5 = pload(q + ln + 320);
            float a6 = pload(q + ln + 384), a7 = pload(q + ln + 448);
            float rr;
            if (st == 0 || st == 3) {
              rr = ((((((a0 + a1) + a2) + a3) + a4) + a5) + a6) + a7;
              #pragma unroll
              for (int m = 1; m < 64; m <<= 1) rr += __shfl_xor(rr, m);
            } else if (st == 1 || st == 4) {
              rr = fmaxf(fmaxf(fmaxf(a0, a1), fmaxf(a2, a3)),
                         fmaxf(fmaxf(a4, a5), fmaxf(a6, a7)));
              #pragma unroll
              for (int m = 1; m < 64; m <<= 1) rr = fmaxf(rr, __shfl_xor(rr, m));
            } else {
              rr = fminf(fminf(fminf(a0, a1), fminf(a2, a3)),
                         fminf(fminf(a4, a5), fminf(a6, a7)));
              #pragma unroll
              for (int m = 1; m < 64; m <<= 1) rr = fminf(rr, __shfl_xor(rr, m));
            }
            r[st] = rr;
          }
          if (ln == 0) {
            const float invN = (wv == 3) ? (1.0f / 4096.0f) : (1.0f / 524288.0f);
            scal[wv][0] = (r[0] * invN) - 0.2f * (r[1] - r[2]);
            scal[wv][1] = (r[3] * invN) - 0.2f * (r[4] - r[5]);
          }
        }
        __syncthreads();
        #pragma unroll
        for (int l2 = 0; l2 < 3; ++l2) {
          const float Vm = scal[l2][0], Vt = scal[l2][1];
          #pragma unroll
          for (int j = 0; j < NB; ++j) {
            float d  = v[l2][j] - Vm;   // v holds v(t-1)
            float sp = logf(1.0f + expf(d * 0.25f));
            tp[l2][j] = (0.01f * d + Vt) + sp;
          }
        }
        if (tid < 8) {
          const float Vm = scal[3][0], Vt = scal[3][1];
          float d  = l4v[tid] - Vm;
          float sp = logf(1.0f + expf(d * 0.25f));
          l4t[tid] = (0.01f * d + Vt) + sp;
        }
        __syncthreads();  // l4t visible before layer-4 phase
      }

      // ---- LIF update + stats for layer l ----
      const float bbx = bL[l];
      float sv = 0.f, svt = 0.f;
      float mxv = -3.402823466e38f, mnv = 3.402823466e38f;
      float mxvt = -3.402823466e38f, mnvt = 3.402823466e38f;
      float sn[NB];
      #pragma unroll
      for (int j = 0; j < NB; ++j) {
        float un = fmaf(u[l][j], 0.5f, acc[j]) + bbx;
        float vp = v[l][j];
        float vd = (vp * 0.75f) * (1.0f - s[l][j]);
        float vn = vd + un;
        float en = expf((vp - vn) / 3.0f) - 1.0f;
        float vt = 0.5f * tp[l][j] + 0.5f * en;
        float sx = (vn > vt) ? 1.0f : 0.0f;
        u[l][j] = un; v[l][j] = vn; s[l][j] = sx;
        sn[j] = sx;
        sv += vn; svt += vt;
        mxv = fmaxf(mxv, vn); mnv = fminf(mnv, vn);
        mxvt = fmaxf(mxvt, vt); mnvt = fminf(mnvt, vt);
      }
      #pragma unroll
      for (int m = 1; m < 64; m <<= 1) {
        sv += __shfl_xor(sv, m);   svt += __shfl_xor(svt, m);
        mxv = fmaxf(mxv, __shfl_xor(mxv, m));  mnv = fminf(mnv, __shfl_xor(mnv, m));
        mxvt = fmaxf(mxvt, __shfl_xor(mxvt, m)); mnvt = fminf(mnvt, __shfl_xor(mnvt, m));
      }
      __syncthreads();   // all GEMM reads of in_lds done; wred slot free
      if ((tid & 63) == 0) {
        int wv = tid >> 6;
        wred[wv][0] = sv;  wred[wv][1] = mxv;  wred[wv][2] = mnv;
        wred[wv][3] = svt; wred[wv][4] = mxvt; wred[wv][5] = mnvt;
      }
      *reinterpret_cast<float4*>(&in_lds[h0 * NB]) =
          make_float4(sn[0], sn[1], sn[2], sn[3]);
      __syncthreads();   // spikes + wred visible
      if (tid < 6) {
        int st = tid; float r;
        if (st == 0 || st == 3)
          r = ((wred[0][st] + wred[1][st]) + wred[2][st]) + wred[3][st];
        else if (st == 1 || st == 4)
          r = fmaxf(fmaxf(wred[0][st], wred[1][st]), fmaxf(wred[2][st], wred[3][st]));
        else
          r = fminf(fminf(wred[0][st], wred[1][st]), fminf(wred[2][st], wred[3][st]));
        pstore(&p.partials[(((size_t)(t & 1) * 4 + l) * 6 + st) * NBLK + blk], r);
      }
      __syncthreads();
    }

    // ---------------- layer 4 (H -> 2) ----------------
    {
      const int g = tid >> 4, c = tid & 15;
      if (g < 8) {
        const int j4 = g >> 1, a4 = g & 1;
        float part = 0.0f;
        #pragma unroll
        for (int i = 0; i < 16; ++i) {
          int k = c + 16 * i;
          part = fmaf(in_lds[k * NB + j4], p.W4[a4 * HH + k], part);
        }
        #pragma unroll
        for (int m = 1; m < 16; m <<= 1) part += __shfl_xor(part, m);
        if (c == 0) {
          float un = fmaf(l4u[g], 0.5f, part) + p.b4[a4];
          float vp = l4v[g];
          float vd = (vp * 0.75f) * (1.0f - l4s[g]);
          float vn = vd + un;
          float en = expf((vp - vn) / 3.0f) - 1.0f;
          float vt = 0.5f * l4t[g] + 0.5f * en;
          float sx = (vn > vt) ? 1.0f : 0.0f;
          l4u[g] = un; l4v[g] = vn; l4s[g] = sx;
          l4acc[g] += sx; l4vn[g] = vn; l4vth[g] = vt;
        }
      }
    }
    __syncthreads();   // layer-4 reads done; l4vn/l4vth visible

    if (t < TT - 1) load_xt(t + 1);   // writes in_lds (safe after sync)

    if (tid == 0) {
      float sv4 = l4vn[0], mx4 = l4vn[0], mn4 = l4vn[0];
      float st4 = l4vth[0], mxt4 = l4vth[0], mnt4 = l4vth[0];
      #pragma unroll
      for (int g2 = 1; g2 < 8; ++g2) {
        sv4 += l4vn[g2]; mx4 = fmaxf(mx4, l4vn[g2]); mn4 = fminf(mn4, l4vn[g2]);
        st4 += l4vth[g2]; mxt4 = fmaxf(mxt4, l4vth[g2]); mnt4 = fminf(mnt4, l4vth[g2]);
      }
      float* pp = p.partials + ((size_t)(t & 1) * 4 + 3) * 6 * NBLK + blk;
      pstore(pp + 0 * NBLK, sv4);  pstore(pp + 1 * NBLK, mx4);  pstore(pp + 2 * NBLK, mn4);
      pstore(pp + 3 * NBLK, st4);  pstore(pp + 4 * NBLK, mxt4); pstore(pp + 5 * NBLK, mnt4);
    }

    if (t < TT - 1) bar_arrive(p.bar, t + 1);  // includes __syncthreads
  }

  __syncthreads();
  if (tid < 8) {
    int j = tid >> 1, a = tid & 1;
    p.out[(size_t)(B0 + j) * AA + a] = l4acc[tid] / 50.0f;
  }
}

extern "C" void kernel_launch(void* const* d_in, const int* in_sizes, int n_in,
                              void* d_out, int out_size, void* d_ws, size_t ws_size,
                              hipStream_t stream) {
  Params p;
  p.x     = (const float*)d_in[0];
  p.fu[0] = (const float*)d_in[1];  p.fv[0] = (const float*)d_in[2];  p.fs[0] = (const float*)d_in[3];
  p.fu[1] = (const float*)d_in[4];  p.fv[1] = (const float*)d_in[5];  p.fs[1] = (const float*)d_in[6];
  p.fu[2] = (const float*)d_in[7];  p.fv[2] = (const float*)d_in[8];  p.fs[2] = (const float*)d_in[9];
  p.f4u   = (const float*)d_in[10]; p.f4v   = (const float*)d_in[11]; p.f4s   = (const float*)d_in[12];
  p.W[0]  = (const float*)d_in[13]; p.bs[0] = (const float*)d_in[14];
  p.W[1]  = (const float*)d_in[15]; p.bs[1] = (const float*)d_in[16];
  p.W[2]  = (const float*)d_in[17]; p.bs[2] = (const float*)d_in[18];
  p.W4    = (const float*)d_in[19]; p.b4    = (const float*)d_in[20];
  p.out   = (float*)d_out;

  float* ws  = (float*)d_ws;
  p.wt3      = ws;                         // 3*69632 = 208896 floats
  p.partials = ws + 208896;                // 2*4*6*512 = 24576 floats
  p.bar      = (unsigned*)(ws + 233472);   // 2 uints (pad to 64)
  p.xT       = ws + 233536;                // 50*524288 floats (optional)
  size_t need = ((size_t)233536 + (size_t)TT * BB * SS) * sizeof(float);
  p.use_xt   = (ws_size >= need) ? 1 : 0;

  hipMemsetAsync((void*)p.bar, 0, 2 * sizeof(unsigned), stream);
  snn_kernel<<<dim3(NBLK), dim3(NTHR), 0, stream>>>(p);
}

// Round 8
// 2808.477 us; speedup vs baseline: 1.8863x; 1.2238x over previous
//
#include <hip/hip_runtime.h>
#include <cstdint>
#include <cstddef>

// Problem dims (fixed)
#define BB 2048
#define SS 256
#define HH 256
#define AA 2
#define TT 50
// Pipeline config: 3 layer-groups x 64 blocks, 32 rows/block, 512 thr (8 waves)
#define NLG   64
#define ROWS  32
#define NTHR  512
#define NGRID 192
#define K4PAD 1088
#define WLAYER (64 * K4PAD)
#define LSTR  36            // in_lds row stride (floats): 144B, b128-aligned, bank-spread

struct Params {
  const float* x;
  const float* fu[3]; const float* fv[3]; const float* fs[3];
  const float* f4u; const float* f4v; const float* f4s;
  const float* W[3]; const float* bs[3];
  const float* W4; const float* b4;
  float* out;
  float* wt3;        // [3][64 k4][256 h][4] padded coalesced tiles
  float* partials;   // [4 ch][2 par][6 st][64 g]
  unsigned* flags;   // [0..127] prod[hop][g], [128..255] ack[hop][g],
                     // [256..258] stats_ctr[L], [260] init_ctr
  float* sbuf;       // [2 hop][2 par][2048][256] spikes
};

__device__ __forceinline__ void pstore(float* p, float v) {
  __hip_atomic_store(p, v, __ATOMIC_RELAXED, __HIP_MEMORY_SCOPE_AGENT);
}
__device__ __forceinline__ float pload(const float* p) {
  return __hip_atomic_load(p, __ATOMIC_RELAXED, __HIP_MEMORY_SCOPE_AGENT);
}
__device__ __forceinline__ unsigned uload_acq(const unsigned* p) {
  return __hip_atomic_load(p, __ATOMIC_ACQUIRE, __HIP_MEMORY_SCOPE_AGENT);
}
__device__ __forceinline__ void ustore_rel(unsigned* p, unsigned v) {
  __hip_atomic_store(p, v, __ATOMIC_RELEASE, __HIP_MEMORY_SCOPE_AGENT);
}
__device__ __forceinline__ void uadd(unsigned* p) {
  __hip_atomic_fetch_add(p, 1u, __ATOMIC_ACQ_REL, __HIP_MEMORY_SCOPE_AGENT);
}

__global__ __launch_bounds__(NTHR, 2)
void snn_pipe(Params p) {
#pragma clang fp contract(off)
  const int tid = threadIdx.x;
  const int blk = blockIdx.x;
  const int L   = blk >> 6;          // 0,1,2  (group 2 also does layer 4)
  const int g   = blk & 63;          // row-block within group
  const int B0  = g * ROWS;

  const int h0  = tid & 127;         // thread covers h0 and h0+128
  const int jgp = tid >> 7;          // 0..3 -> j0 = 8*jgp (wave-uniform)
  const int j0  = jgp << 3;
  const int sid = tid & 255;         // staging map
  const int jq  = tid >> 8;          // 0..1

  __shared__ __align__(16) float in_lds[HH * LSTR];      // [k][j(32), pad]
  __shared__ __align__(16) float s3_lds[ROWS * 257];     // L2 group: s3 [j][h]
  __shared__ float wred[8][6];
  __shared__ float scal[2][2];       // [0]=own layer (Vm,Vt), [1]=layer4 (L==2)
  __shared__ float l4u[64], l4v[64], l4s[64], l4t[64], l4acc[64], l4vn[64], l4vth[64];

  // ---- prologue: build coalesced W tiles (first 32 blocks) ----
  {
    const int gtid = blk * NTHR + tid;
    if (gtid < 16384) {
      const int h = gtid & 255, k4 = gtid >> 8;
      #pragma unroll
      for (int l = 0; l < 3; ++l) {
        float4 w = *reinterpret_cast<const float4*>(p.W[l] + (size_t)h * 256 + k4 * 4);
        *reinterpret_cast<float4*>(p.wt3 + (size_t)l * WLAYER + (size_t)k4 * K4PAD + h * 4) = w;
      }
    }
  }

  // ---- per-thread state: own layer, 2 h x 8 j cells ----
  float u[2][8], v[2][8], s[2][8], tp[2][8];
  #pragma unroll
  for (int hh = 0; hh < 2; ++hh)
    #pragma unroll
    for (int jj = 0; jj < 8; ++jj) {
      size_t idx = (size_t)(B0 + j0 + jj) * HH + h0 + 128 * hh;
      u[hh][jj] = p.fu[L][idx];
      v[hh][jj] = p.fv[L][idx];
      s[hh][jj] = p.fs[L][idx];
      tp[hh][jj] = 0.5f;
    }
  const float bL[2] = { p.bs[L][h0], p.bs[L][h0 + 128] };
  if (L == 2 && tid < 64) {
    size_t idx = (size_t)(B0 + (tid >> 1)) * AA + (tid & 1);
    l4u[tid] = p.f4u[idx]; l4v[tid] = p.f4v[idx]; l4s[tid] = p.f4s[idx];
    l4t[tid] = 0.5f; l4acc[tid] = 0.0f;
  }
  __syncthreads();

  // ---- one-time global init barrier (wt3 visible) ----
  if (tid == 0) {
    uadd(&p.flags[260]);
    while (uload_acq(&p.flags[260]) < (unsigned)NGRID) __builtin_amdgcn_s_sleep(2);
  }
  __syncthreads();

  // L0: prefetch x(t=0) into registers
  float xreg[16];
  if (L == 0) {
    #pragma unroll
    for (int i = 0; i < 16; ++i)
      xreg[i] = p.x[((size_t)(B0 + jq * 16 + i) * SS + sid) * TT + 0];
  }

  const float* wpf0 = p.wt3 + (size_t)L * WLAYER + (h0 << 2);
  const float* wpf1 = wpf0 + (128 << 2);
  float* sb_in  = (L > 0) ? p.sbuf + (size_t)(L - 1) * 2 * BB * HH : nullptr;
  float* sb_out = (L < 2) ? p.sbuf + (size_t)L * 2 * BB * HH : nullptr;

  #pragma unroll 1
  for (int t = 0; t < TT; ++t) {
    // ---- 1. stage input into in_lds ----
    if (L == 0) {
      #pragma unroll
      for (int i = 0; i < 16; ++i)
        in_lds[sid * LSTR + jq * 16 + i] = xreg[i];
      if (t < TT - 1) {
        #pragma unroll
        for (int i = 0; i < 16; ++i)
          xreg[i] = p.x[((size_t)(B0 + jq * 16 + i) * SS + sid) * TT + (t + 1)];
      }
    } else {
      const int hop = L - 1;
      if (tid == 0) {
        while (uload_acq(&p.flags[hop * 64 + g]) < (unsigned)(t + 1))
          __builtin_amdgcn_s_sleep(2);
      }
      __syncthreads();
      const float* src = sb_in + (size_t)(t & 1) * BB * HH;
      #pragma unroll
      for (int i = 0; i < 16; ++i)
        in_lds[sid * LSTR + jq * 16 + i] =
            pload(src + ((size_t)(B0 + jq * 16 + i) << 8) + sid);
      __syncthreads();   // staging reads done
      if (tid == 0) ustore_rel(&p.flags[128 + hop * 64 + g], (unsigned)(t + 1));
    }
    __syncthreads();     // in_lds ready

    // ---- 2. GEMM: acc[hh][jj] = sum_k W[h][k]*in[k][j], ascending k ----
    float acc[2][8];
    #pragma unroll
    for (int hh = 0; hh < 2; ++hh)
      #pragma unroll
      for (int jj = 0; jj < 8; ++jj) acc[hh][jj] = 0.0f;
    #pragma unroll 2
    for (int k4 = 0; k4 < 64; ++k4) {
      float4 w0 = *reinterpret_cast<const float4*>(wpf0 + (size_t)k4 * K4PAD);
      float4 w1 = *reinterpret_cast<const float4*>(wpf1 + (size_t)k4 * K4PAD);
      #pragma unroll
      for (int q = 0; q < 4; ++q) {
        const int k = k4 * 4 + q;
        const float* row = &in_lds[k * LSTR + j0];
        float4 ia = *reinterpret_cast<const float4*>(row);
        float4 ib = *reinterpret_cast<const float4*>(row + 4);
        const float wa = (q == 0) ? w0.x : (q == 1) ? w0.y : (q == 2) ? w0.z : w0.w;
        const float wb = (q == 0) ? w1.x : (q == 1) ? w1.y : (q == 2) ? w1.z : w1.w;
        acc[0][0] = fmaf(ia.x, wa, acc[0][0]); acc[0][1] = fmaf(ia.y, wa, acc[0][1]);
        acc[0][2] = fmaf(ia.z, wa, acc[0][2]); acc[0][3] = fmaf(ia.w, wa, acc[0][3]);
        acc[0][4] = fmaf(ib.x, wa, acc[0][4]); acc[0][5] = fmaf(ib.y, wa, acc[0][5]);
        acc[0][6] = fmaf(ib.z, wa, acc[0][6]); acc[0][7] = fmaf(ib.w, wa, acc[0][7]);
        acc[1][0] = fmaf(ia.x, wb, acc[1][0]); acc[1][1] = fmaf(ia.y, wb, acc[1][1]);
        acc[1][2] = fmaf(ia.z, wb, acc[1][2]); acc[1][3] = fmaf(ia.w, wb, acc[1][3]);
        acc[1][4] = fmaf(ib.x, wb, acc[1][4]); acc[1][5] = fmaf(ib.y, wb, acc[1][5]);
        acc[1][6] = fmaf(ib.z, wb, acc[1][6]); acc[1][7] = fmaf(ib.w, wb, acc[1][7]);
      }
    }

    // ---- 3. stats(t-1): group sync, cross-block reduce, temporal update ----
    if (t > 0) {
      if (tid == 0) {
        while (uload_acq(&p.flags[256 + L]) < 64u * (unsigned)t)
          __builtin_amdgcn_s_sleep(2);
      }
      __syncthreads();
      {
        const int wv = tid >> 6, ln = tid & 63;
        if (wv == 0 || (wv == 1 && L == 2)) {
          const int ch = (wv == 0) ? L : 3;
          const float* pb = p.partials + (size_t)(ch * 2 + ((t - 1) & 1)) * 6 * 64;
          float r[6];
          #pragma unroll
          for (int st = 0; st < 6; ++st) {
            float rr = pload(pb + st * 64 + ln);
            if (st == 0 || st == 3) {
              #pragma unroll
              for (int m = 1; m < 64; m <<= 1) rr += __shfl_xor(rr, m);
            } else if (st == 1 || st == 4) {
              #pragma unroll
              for (int m = 1; m < 64; m <<= 1) rr = fmaxf(rr, __shfl_xor(rr, m));
            } else {
              #pragma unroll
              for (int m = 1; m < 64; m <<= 1) rr = fminf(rr, __shfl_xor(rr, m));
            }
            r[st] = rr;
          }
          if (ln == 0) {
            const float invN = (ch == 3) ? (1.0f / 4096.0f) : (1.0f / 524288.0f);
            scal[wv][0] = (r[0] * invN) - 0.2f * (r[1] - r[2]);
            scal[wv][1] = (r[3] * invN) - 0.2f * (r[4] - r[5]);
          }
        }
      }
      __syncthreads();
      {
        const float Vm = scal[0][0], Vt = scal[0][1];
        #pragma unroll
        for (int hh = 0; hh < 2; ++hh)
          #pragma unroll
          for (int jj = 0; jj < 8; ++jj) {
            float d = v[hh][jj] - Vm;           // v holds v(t-1)
            float sp = logf(1.0f + expf(d * 0.25f));
            tp[hh][jj] = (0.01f * d + Vt) + sp;
          }
      }
      if (L == 2 && tid < 64) {
        const float Vm = scal[1][0], Vt = scal[1][1];
        float d = l4v[tid] - Vm;
        float sp = logf(1.0f + expf(d * 0.25f));
        l4t[tid] = (0.01f * d + Vt) + sp;
      }
      __syncthreads();
    }

    // ---- 4. LIF + per-thread/wave stats ----
    float sv = 0.f, svt = 0.f;
    float mxv = -3.402823466e38f, mnv = 3.402823466e38f;
    float mxvt = -3.402823466e38f, mnvt = 3.402823466e38f;
    float sn[2][8];
    #pragma unroll
    for (int hh = 0; hh < 2; ++hh) {
      const float bbx = bL[hh];
      #pragma unroll
      for (int jj = 0; jj < 8; ++jj) {
        float un = fmaf(u[hh][jj], 0.5f, acc[hh][jj]) + bbx;
        float vp = v[hh][jj];
        float vd = (vp * 0.75f) * (1.0f - s[hh][jj]);
        float vn = vd + un;
        float en = expf((vp - vn) / 3.0f) - 1.0f;
        float vt = 0.5f * tp[hh][jj] + 0.5f * en;
        float sx = (vn > vt) ? 1.0f : 0.0f;
        u[hh][jj] = un; v[hh][jj] = vn; s[hh][jj] = sx;
        sn[hh][jj] = sx;
        sv += vn; svt += vt;
        mxv = fmaxf(mxv, vn); mnv = fminf(mnv, vn);
        mxvt = fmaxf(mxvt, vt); mnvt = fminf(mnvt, vt);
      }
    }
    #pragma unroll
    for (int m = 1; m < 64; m <<= 1) {
      sv += __shfl_xor(sv, m);   svt += __shfl_xor(svt, m);
      mxv = fmaxf(mxv, __shfl_xor(mxv, m));  mnv = fminf(mnv, __shfl_xor(mnv, m));
      mxvt = fmaxf(mxvt, __shfl_xor(mxvt, m)); mnvt = fminf(mnvt, __shfl_xor(mnvt, m));
    }
    if ((tid & 63) == 0) {
      int wv = tid >> 6;
      wred[wv][0] = sv;  wred[wv][1] = mxv;  wred[wv][2] = mnv;
      wred[wv][3] = svt; wred[wv][4] = mxvt; wred[wv][5] = mnvt;
    }

    // ---- 5. publish spikes ----
    if (L < 2) {
      if (t >= 2 && tid == 0) {
        while (uload_acq(&p.flags[128 + L * 64 + g]) < (unsigned)(t - 1))
          __builtin_amdgcn_s_sleep(2);
      }
      __syncthreads();   // ack ok + wred visible + GEMM's in_lds reads done
      float* dst = sb_out + (size_t)(t & 1) * BB * HH;
      #pragma unroll
      for (int hh = 0; hh < 2; ++hh)
        #pragma unroll
        for (int jj = 0; jj < 8; ++jj)
          pstore(dst + (size_t)(B0 + j0 + jj) * HH + h0 + 128 * hh, sn[hh][jj]);
      __syncthreads();   // stores drained (vmcnt 0 at barrier)
      if (tid == 0) ustore_rel(&p.flags[L * 64 + g], (unsigned)(t + 1));
    } else {
      __syncthreads();   // wred visible
      #pragma unroll
      for (int hh = 0; hh < 2; ++hh)
        #pragma unroll
        for (int jj = 0; jj < 8; ++jj)
          s3_lds[(j0 + jj) * 257 + h0 + 128 * hh] = sn[hh][jj];
      __syncthreads();   // s3 ready
    }

    // ---- 6. block stats partial -> global ----
    if (tid < 6) {
      const int st = tid;
      float r = wred[0][st];
      if (st == 0 || st == 3) {
        #pragma unroll
        for (int wv = 1; wv < 8; ++wv) r = r + wred[wv][st];
      } else if (st == 1 || st == 4) {
        #pragma unroll
        for (int wv = 1; wv < 8; ++wv) r = fmaxf(r, wred[wv][st]);
      } else {
        #pragma unroll
        for (int wv = 1; wv < 8; ++wv) r = fminf(r, wred[wv][st]);
      }
      pstore(p.partials + (size_t)(L * 2 + (t & 1)) * 6 * 64 + st * 64 + g, r);
    }

    // ---- 7. layer 4 (L2 group only) ----
    if (L == 2) {
      const int d = tid >> 3, c = tid & 7;
      const int j4 = d >> 1, a4 = d & 1;
      float part = 0.0f;
      #pragma unroll
      for (int i = 0; i < 32; ++i) {
        int k = c + 8 * i;
        part = fmaf(s3_lds[j4 * 257 + k], p.W4[a4 * HH + k], part);
      }
      #pragma unroll
      for (int m = 1; m < 8; m <<= 1) part += __shfl_xor(part, m);
      if (c == 0) {
        float un = fmaf(l4u[d], 0.5f, part) + p.b4[a4];
        float vp = l4v[d];
        float vd = (vp * 0.75f) * (1.0f - l4s[d]);
        float vn = vd + un;
        float en = expf((vp - vn) / 3.0f) - 1.0f;
        float vt = 0.5f * l4t[d] + 0.5f * en;
        float sx = (vn > vt) ? 1.0f : 0.0f;
        l4u[d] = un; l4v[d] = vn; l4s[d] = sx;
        l4acc[d] += sx; l4vn[d] = vn; l4vth[d] = vt;
      }
      __syncthreads();
      if (tid == 0) {
        float sv4 = l4vn[0], mx4 = l4vn[0], mn4 = l4vn[0];
        float st4 = l4vth[0], mxt4 = l4vth[0], mnt4 = l4vth[0];
        #pragma unroll
        for (int d2 = 1; d2 < 64; ++d2) {
          sv4 += l4vn[d2]; mx4 = fmaxf(mx4, l4vn[d2]); mn4 = fminf(mn4, l4vn[d2]);
          st4 += l4vth[d2]; mxt4 = fmaxf(mxt4, l4vth[d2]); mnt4 = fminf(mnt4, l4vth[d2]);
        }
        float* pp = p.partials + (size_t)(3 * 2 + (t & 1)) * 6 * 64 + g;
        pstore(pp + 0 * 64, sv4);  pstore(pp + 1 * 64, mx4);  pstore(pp + 2 * 64, mn4);
        pstore(pp + 3 * 64, st4);  pstore(pp + 4 * 64, mxt4); pstore(pp + 5 * 64, mnt4);
      }
    }

    // ---- 8. arrive group stats counter ----
    __syncthreads();     // drain partial pstores from all writers
    if (tid == 0) uadd(&p.flags[256 + L]);
  }

  if (L == 2 && tid < 64)
    p.out[(size_t)(B0 + (tid >> 1)) * AA + (tid & 1)] = l4acc[tid] / 50.0f;
}

extern "C" void kernel_launch(void* const* d_in, const int* in_sizes, int n_in,
                              void* d_out, int out_size, void* d_ws, size_t ws_size,
                              hipStream_t stream) {
  Params p;
  p.x     = (const float*)d_in[0];
  p.fu[0] = (const float*)d_in[1];  p.fv[0] = (const float*)d_in[2];  p.fs[0] = (const float*)d_in[3];
  p.fu[1] = (const float*)d_in[4];  p.fv[1] = (const float*)d_in[5];  p.fs[1] = (const float*)d_in[6];
  p.fu[2] = (const float*)d_in[7];  p.fv[2] = (const float*)d_in[8];  p.fs[2] = (const float*)d_in[9];
  p.f4u   = (const float*)d_in[10]; p.f4v   = (const float*)d_in[11]; p.f4s   = (const float*)d_in[12];
  p.W[0]  = (const float*)d_in[13]; p.bs[0] = (const float*)d_in[14];
  p.W[1]  = (const float*)d_in[15]; p.bs[1] = (const float*)d_in[16];
  p.W[2]  = (const float*)d_in[17]; p.bs[2] = (const float*)d_in[18];
  p.W4    = (const float*)d_in[19]; p.b4    = (const float*)d_in[20];
  p.out   = (float*)d_out;

  float* ws   = (float*)d_ws;
  p.wt3       = ws;                          // 3*69632 = 208896 floats
  p.partials  = ws + 208896;                 // 4*2*6*64 = 3072
  p.flags     = (unsigned*)(ws + 211968);    // 1024 uints
  p.sbuf      = ws + 212992;                 // 2*2*2048*256 = 2,097,152 floats

  hipMemsetAsync((void*)p.flags, 0, 4096, stream);
  snn_pipe<<<dim3(NGRID), dim3(NTHR), 0, stream>>>(p);
}

// Round 9
// 2778.601 us; speedup vs baseline: 1.9066x; 1.0108x over previous
//
#include <hip/hip_runtime.h>
#include <cstdint>
#include <cstddef>

// Problem dims (fixed)
#define BB 2048
#define SS 256
#define HH 256
#define AA 2
#define TT 50
// Pipeline config: 3 layer-groups x 64 blocks, 32 rows/block, 512 thr (8 waves)
#define NLG   64
#define ROWS  32
#define NTHR  512
#define NGRID 192
#define K4PAD 1088
#define WLAYER (64 * K4PAD)
#define LSTR  36            // in_lds row stride (floats): 144B, b128-aligned

struct Params {
  const float* x;
  const float* fu[3]; const float* fv[3]; const float* fs[3];
  const float* f4u; const float* f4v; const float* f4s;
  const float* W[3]; const float* bs[3];
  const float* W4; const float* b4;
  float* out;
  float* wt3;        // [3][64 k4][256 h][4] padded coalesced tiles
  float* partials;   // [4 ch][2 par][6 st][64 g]
  unsigned* flags;   // [0..127] prod[hop][g], [128..255] ack[hop][g],
                     // [256..258] stats_ctr[L], [260] init_ctr
  float* sbuf;       // [2 hop][2 par][2048][256] spikes
  float* xT;         // [TT][BB*SS] transposed input (optional)
  int use_xt;
};

__device__ __forceinline__ void pstore(float* p, float v) {
  __hip_atomic_store(p, v, __ATOMIC_RELAXED, __HIP_MEMORY_SCOPE_AGENT);
}
__device__ __forceinline__ float pload(const float* p) {
  return __hip_atomic_load(p, __ATOMIC_RELAXED, __HIP_MEMORY_SCOPE_AGENT);
}
__device__ __forceinline__ unsigned uload_acq(const unsigned* p) {
  return __hip_atomic_load(p, __ATOMIC_ACQUIRE, __HIP_MEMORY_SCOPE_AGENT);
}
__device__ __forceinline__ void ustore_rel(unsigned* p, unsigned v) {
  __hip_atomic_store(p, v, __ATOMIC_RELEASE, __HIP_MEMORY_SCOPE_AGENT);
}
__device__ __forceinline__ void uadd(unsigned* p) {
  __hip_atomic_fetch_add(p, 1u, __ATOMIC_ACQ_REL, __HIP_MEMORY_SCOPE_AGENT);
}

__global__ __launch_bounds__(NTHR, 2)
void snn_pipe(Params p) {
#pragma clang fp contract(off)
  const int tid = threadIdx.x;
  const int blk = blockIdx.x;
  const int L   = blk >> 6;          // 0,1,2  (group 2 also does layer 4)
  const int g   = blk & 63;          // row-block within group
  const int B0  = g * ROWS;

  const int h0  = tid & 127;         // thread covers h0 and h0+128
  const int jgp = tid >> 7;          // 0..3 -> j0 = 8*jgp (wave-uniform)
  const int j0  = jgp << 3;
  const int sid = tid & 255;         // staging map
  const int jq  = tid >> 8;          // 0..1

  __shared__ __align__(16) float in_lds[HH * LSTR];      // [k][j(32), pad]
  __shared__ __align__(16) float s3_lds[ROWS * 257];     // L2 group: s3 [j][h]
  __shared__ float wred[8][6];
  __shared__ float scal[2][2];       // [0]=own layer (Vm,Vt), [1]=layer4 (L==2)
  __shared__ float l4u[64], l4v[64], l4s[64], l4t[64], l4acc[64], l4vn[64], l4vth[64];

  // ---- prologue 1: build coalesced W tiles ----
  {
    const int gtid = blk * NTHR + tid;
    if (gtid < 16384) {
      const int h = gtid & 255, k4 = gtid >> 8;
      #pragma unroll
      for (int l = 0; l < 3; ++l) {
        float4 w = *reinterpret_cast<const float4*>(p.W[l] + (size_t)h * 256 + k4 * 4);
        *reinterpret_cast<float4*>(p.wt3 + (size_t)l * WLAYER + (size_t)k4 * K4PAD + h * 4) = w;
      }
    }
    // ---- prologue 2: transpose x -> xT[t][b*SS+s] (coalesced per-t writes) ----
    if (p.use_xt) {
      for (int sid0 = gtid; sid0 < BB * SS; sid0 += NGRID * NTHR) {
        const float* src = p.x + (size_t)sid0 * TT;
        #pragma unroll 1
        for (int t = 0; t < TT; ++t)
          p.xT[(size_t)t * (BB * SS) + sid0] = src[t];
      }
    }
  }

  // ---- per-thread state: own layer, 2 h x 8 j cells ----
  float u[2][8], v[2][8], s[2][8], tp[2][8];
  #pragma unroll
  for (int hh = 0; hh < 2; ++hh)
    #pragma unroll
    for (int jj = 0; jj < 8; ++jj) {
      size_t idx = (size_t)(B0 + j0 + jj) * HH + h0 + 128 * hh;
      u[hh][jj] = p.fu[L][idx];
      v[hh][jj] = p.fv[L][idx];
      s[hh][jj] = p.fs[L][idx];
      tp[hh][jj] = 0.5f;
    }
  const float bL[2] = { p.bs[L][h0], p.bs[L][h0 + 128] };
  if (L == 2 && tid < 64) {
    size_t idx = (size_t)(B0 + (tid >> 1)) * AA + (tid & 1);
    l4u[tid] = p.f4u[idx]; l4v[tid] = p.f4v[idx]; l4s[tid] = p.f4s[idx];
    l4t[tid] = 0.5f; l4acc[tid] = 0.0f;
  }
  __syncthreads();

  // ---- one-time global init barrier (wt3 + xT visible) ----
  if (tid == 0) {
    uadd(&p.flags[260]);
    while (uload_acq(&p.flags[260]) < (unsigned)NGRID) __builtin_amdgcn_s_sleep(2);
  }
  __syncthreads();

  // L0: prefetch x(t=0) into registers
  float xreg[16];
  if (L == 0) {
    if (p.use_xt) {
      const float* src = p.xT + (size_t)B0 * SS;
      #pragma unroll
      for (int i = 0; i < 16; ++i)
        xreg[i] = src[((size_t)(jq * 16 + i) << 8) + sid];
    } else {
      #pragma unroll
      for (int i = 0; i < 16; ++i)
        xreg[i] = p.x[((size_t)(B0 + jq * 16 + i) * SS + sid) * TT + 0];
    }
  }

  const float* wpf0 = p.wt3 + (size_t)L * WLAYER + (h0 << 2);
  const float* wpf1 = wpf0 + (128 << 2);
  float* sb_in  = (L > 0) ? p.sbuf + (size_t)(L - 1) * 2 * BB * HH : nullptr;
  float* sb_out = (L < 2) ? p.sbuf + (size_t)L * 2 * BB * HH : nullptr;

  #pragma unroll 1
  for (int t = 0; t < TT; ++t) {
    // ---- 1. stage input into in_lds ----
    if (L == 0) {
      #pragma unroll
      for (int i = 0; i < 16; ++i)
        in_lds[sid * LSTR + jq * 16 + i] = xreg[i];
      if (t < TT - 1) {
        if (p.use_xt) {
          const float* src = p.xT + (size_t)(t + 1) * (BB * SS) + (size_t)B0 * SS;
          #pragma unroll
          for (int i = 0; i < 16; ++i)
            xreg[i] = src[((size_t)(jq * 16 + i) << 8) + sid];
        } else {
          #pragma unroll
          for (int i = 0; i < 16; ++i)
            xreg[i] = p.x[((size_t)(B0 + jq * 16 + i) * SS + sid) * TT + (t + 1)];
        }
      }
    } else {
      const int hop = L - 1;
      if (tid == 0) {
        while (uload_acq(&p.flags[hop * 64 + g]) < (unsigned)(t + 1))
          __builtin_amdgcn_s_sleep(2);
      }
      __syncthreads();
      const float* src = sb_in + (size_t)(t & 1) * BB * HH;
      #pragma unroll
      for (int i = 0; i < 16; ++i)
        in_lds[sid * LSTR + jq * 16 + i] =
            pload(src + ((size_t)(B0 + jq * 16 + i) << 8) + sid);
      __syncthreads();   // staging reads done
      if (tid == 0) ustore_rel(&p.flags[128 + hop * 64 + g], (unsigned)(t + 1));
    }
    __syncthreads();     // in_lds ready

    // ---- 2. GEMM: acc[hh][jj] = sum_k W[h][k]*in[k][j], ascending k ----
    float acc[2][8];
    #pragma unroll
    for (int hh = 0; hh < 2; ++hh)
      #pragma unroll
      for (int jj = 0; jj < 8; ++jj) acc[hh][jj] = 0.0f;
    #pragma unroll 2
    for (int k4 = 0; k4 < 64; ++k4) {
      float4 w0 = *reinterpret_cast<const float4*>(wpf0 + (size_t)k4 * K4PAD);
      float4 w1 = *reinterpret_cast<const float4*>(wpf1 + (size_t)k4 * K4PAD);
      #pragma unroll
      for (int q = 0; q < 4; ++q) {
        const int k = k4 * 4 + q;
        const float* row = &in_lds[k * LSTR + j0];
        float4 ia = *reinterpret_cast<const float4*>(row);
        float4 ib = *reinterpret_cast<const float4*>(row + 4);
        const float wa = (q == 0) ? w0.x : (q == 1) ? w0.y : (q == 2) ? w0.z : w0.w;
        const float wb = (q == 0) ? w1.x : (q == 1) ? w1.y : (q == 2) ? w1.z : w1.w;
        acc[0][0] = fmaf(ia.x, wa, acc[0][0]); acc[0][1] = fmaf(ia.y, wa, acc[0][1]);
        acc[0][2] = fmaf(ia.z, wa, acc[0][2]); acc[0][3] = fmaf(ia.w, wa, acc[0][3]);
        acc[0][4] = fmaf(ib.x, wa, acc[0][4]); acc[0][5] = fmaf(ib.y, wa, acc[0][5]);
        acc[0][6] = fmaf(ib.z, wa, acc[0][6]); acc[0][7] = fmaf(ib.w, wa, acc[0][7]);
        acc[1][0] = fmaf(ia.x, wb, acc[1][0]); acc[1][1] = fmaf(ia.y, wb, acc[1][1]);
        acc[1][2] = fmaf(ia.z, wb, acc[1][2]); acc[1][3] = fmaf(ia.w, wb, acc[1][3]);
        acc[1][4] = fmaf(ib.x, wb, acc[1][4]); acc[1][5] = fmaf(ib.y, wb, acc[1][5]);
        acc[1][6] = fmaf(ib.z, wb, acc[1][6]); acc[1][7] = fmaf(ib.w, wb, acc[1][7]);
      }
    }

    // ---- 3. stats(t-1): group sync, cross-block reduce, temporal update ----
    if (t > 0) {
      if (tid == 0) {
        while (uload_acq(&p.flags[256 + L]) < 64u * (unsigned)t)
          __builtin_amdgcn_s_sleep(2);
      }
      __syncthreads();
      {
        const int wv = tid >> 6, ln = tid & 63;
        if (wv == 0 || (wv == 1 && L == 2)) {
          const int ch = (wv == 0) ? L : 3;
          const float* pb = p.partials + (size_t)(ch * 2 + ((t - 1) & 1)) * 6 * 64;
          float r[6];
          #pragma unroll
          for (int st = 0; st < 6; ++st) {
            float rr = pload(pb + st * 64 + ln);
            if (st == 0 || st == 3) {
              #pragma unroll
              for (int m = 1; m < 64; m <<= 1) rr += __shfl_xor(rr, m);
            } else if (st == 1 || st == 4) {
              #pragma unroll
              for (int m = 1; m < 64; m <<= 1) rr = fmaxf(rr, __shfl_xor(rr, m));
            } else {
              #pragma unroll
              for (int m = 1; m < 64; m <<= 1) rr = fminf(rr, __shfl_xor(rr, m));
            }
            r[st] = rr;
          }
          if (ln == 0) {
            const float invN = (ch == 3) ? (1.0f / 4096.0f) : (1.0f / 524288.0f);
            scal[wv][0] = (r[0] * invN) - 0.2f * (r[1] - r[2]);
            scal[wv][1] = (r[3] * invN) - 0.2f * (r[4] - r[5]);
          }
        }
      }
      __syncthreads();
      {
        const float Vm = scal[0][0], Vt = scal[0][1];
        #pragma unroll
        for (int hh = 0; hh < 2; ++hh)
          #pragma unroll
          for (int jj = 0; jj < 8; ++jj) {
            float d = v[hh][jj] - Vm;           // v holds v(t-1)
            float sp = logf(1.0f + expf(d * 0.25f));
            tp[hh][jj] = (0.01f * d + Vt) + sp;
          }
      }
      if (L == 2 && tid < 64) {
        const float Vm = scal[1][0], Vt = scal[1][1];
        float d = l4v[tid] - Vm;
        float sp = logf(1.0f + expf(d * 0.25f));
        l4t[tid] = (0.01f * d + Vt) + sp;
      }
      __syncthreads();
    }

    // ---- 4. LIF + per-thread/wave stats ----
    float sv = 0.f, svt = 0.f;
    float mxv = -3.402823466e38f, mnv = 3.402823466e38f;
    float mxvt = -3.402823466e38f, mnvt = 3.402823466e38f;
    float sn[2][8];
    #pragma unroll
    for (int hh = 0; hh < 2; ++hh) {
      const float bbx = bL[hh];
      #pragma unroll
      for (int jj = 0; jj < 8; ++jj) {
        float un = fmaf(u[hh][jj], 0.5f, acc[hh][jj]) + bbx;
        float vp = v[hh][jj];
        float vd = (vp * 0.75f) * (1.0f - s[hh][jj]);
        float vn = vd + un;
        float en = expf((vp - vn) / 3.0f) - 1.0f;
        float vt = 0.5f * tp[hh][jj] + 0.5f * en;
        float sx = (vn > vt) ? 1.0f : 0.0f;
        u[hh][jj] = un; v[hh][jj] = vn; s[hh][jj] = sx;
        sn[hh][jj] = sx;
        sv += vn; svt += vt;
        mxv = fmaxf(mxv, vn); mnv = fminf(mnv, vn);
        mxvt = fmaxf(mxvt, vt); mnvt = fminf(mnvt, vt);
      }
    }
    #pragma unroll
    for (int m = 1; m < 64; m <<= 1) {
      sv += __shfl_xor(sv, m);   svt += __shfl_xor(svt, m);
      mxv = fmaxf(mxv, __shfl_xor(mxv, m));  mnv = fminf(mnv, __shfl_xor(mnv, m));
      mxvt = fmaxf(mxvt, __shfl_xor(mxvt, m)); mnvt = fminf(mnvt, __shfl_xor(mnvt, m));
    }
    if ((tid & 63) == 0) {
      int wv = tid >> 6;
      wred[wv][0] = sv;  wred[wv][1] = mxv;  wred[wv][2] = mnv;
      wred[wv][3] = svt; wred[wv][4] = mxvt; wred[wv][5] = mnvt;
    }

    // ---- 5. publish spikes ----
    if (L < 2) {
      if (t >= 2 && tid == 0) {
        while (uload_acq(&p.flags[128 + L * 64 + g]) < (unsigned)(t - 1))
          __builtin_amdgcn_s_sleep(2);
      }
      __syncthreads();   // ack ok + wred visible + GEMM's in_lds reads done
      float* dst = sb_out + (size_t)(t & 1) * BB * HH;
      #pragma unroll
      for (int hh = 0; hh < 2; ++hh)
        #pragma unroll
        for (int jj = 0; jj < 8; ++jj)
          pstore(dst + (size_t)(B0 + j0 + jj) * HH + h0 + 128 * hh, sn[hh][jj]);
      __syncthreads();   // stores drained (vmcnt 0 at barrier)
      if (tid == 0) ustore_rel(&p.flags[L * 64 + g], (unsigned)(t + 1));
    } else {
      __syncthreads();   // wred visible
      #pragma unroll
      for (int hh = 0; hh < 2; ++hh)
        #pragma unroll
        for (int jj = 0; jj < 8; ++jj)
          s3_lds[(j0 + jj) * 257 + h0 + 128 * hh] = sn[hh][jj];
      __syncthreads();   // s3 ready
    }

    // ---- 6. block stats partial -> global ----
    if (tid < 6) {
      const int st = tid;
      float r = wred[0][st];
      if (st == 0 || st == 3) {
        #pragma unroll
        for (int wv = 1; wv < 8; ++wv) r = r + wred[wv][st];
      } else if (st == 1 || st == 4) {
        #pragma unroll
        for (int wv = 1; wv < 8; ++wv) r = fmaxf(r, wred[wv][st]);
      } else {
        #pragma unroll
        for (int wv = 1; wv < 8; ++wv) r = fminf(r, wred[wv][st]);
      }
      pstore(p.partials + (size_t)(L * 2 + (t & 1)) * 6 * 64 + st * 64 + g, r);
    }

    // ---- 7. layer 4 (L2 group only) ----
    if (L == 2) {
      const int d = tid >> 3, c = tid & 7;
      const int j4 = d >> 1, a4 = d & 1;
      float part = 0.0f;
      #pragma unroll
      for (int i = 0; i < 32; ++i) {
        int k = c + 8 * i;
        part = fmaf(s3_lds[j4 * 257 + k], p.W4[a4 * HH + k], part);
      }
      #pragma unroll
      for (int m = 1; m < 8; m <<= 1) part += __shfl_xor(part, m);
      if (c == 0) {
        float un = fmaf(l4u[d], 0.5f, part) + p.b4[a4];
        float vp = l4v[d];
        float vd = (vp * 0.75f) * (1.0f - l4s[d]);
        float vn = vd + un;
        float en = expf((vp - vn) / 3.0f) - 1.0f;
        float vt = 0.5f * l4t[d] + 0.5f * en;
        float sx = (vn > vt) ? 1.0f : 0.0f;
        l4u[d] = un; l4v[d] = vn; l4s[d] = sx;
        l4acc[d] += sx; l4vn[d] = vn; l4vth[d] = vt;
      }
      __syncthreads();
      if (tid == 0) {
        float sv4 = l4vn[0], mx4 = l4vn[0], mn4 = l4vn[0];
        float st4 = l4vth[0], mxt4 = l4vth[0], mnt4 = l4vth[0];
        #pragma unroll
        for (int d2 = 1; d2 < 64; ++d2) {
          sv4 += l4vn[d2]; mx4 = fmaxf(mx4, l4vn[d2]); mn4 = fminf(mn4, l4vn[d2]);
          st4 += l4vth[d2]; mxt4 = fmaxf(mxt4, l4vth[d2]); mnt4 = fminf(mnt4, l4vth[d2]);
        }
        float* pp = p.partials + (size_t)(3 * 2 + (t & 1)) * 6 * 64 + g;
        pstore(pp + 0 * 64, sv4);  pstore(pp + 1 * 64, mx4);  pstore(pp + 2 * 64, mn4);
        pstore(pp + 3 * 64, st4);  pstore(pp + 4 * 64, mxt4); pstore(pp + 5 * 64, mnt4);
      }
    }

    // ---- 8. arrive group stats counter ----
    __syncthreads();     // drain partial pstores from all writers
    if (tid == 0) uadd(&p.flags[256 + L]);
  }

  if (L == 2 && tid < 64)
    p.out[(size_t)(B0 + (tid >> 1)) * AA + (tid & 1)] = l4acc[tid] / 50.0f;
}

extern "C" void kernel_launch(void* const* d_in, const int* in_sizes, int n_in,
                              void* d_out, int out_size, void* d_ws, size_t ws_size,
                              hipStream_t stream) {
  Params p;
  p.x     = (const float*)d_in[0];
  p.fu[0] = (const float*)d_in[1];  p.fv[0] = (const float*)d_in[2];  p.fs[0] = (const float*)d_in[3];
  p.fu[1] = (const float*)d_in[4];  p.fv[1] = (const float*)d_in[5];  p.fs[1] = (const float*)d_in[6];
  p.fu[2] = (const float*)d_in[7];  p.fv[2] = (const float*)d_in[8];  p.fs[2] = (const float*)d_in[9];
  p.f4u   = (const float*)d_in[10]; p.f4v   = (const float*)d_in[11]; p.f4s   = (const float*)d_in[12];
  p.W[0]  = (const float*)d_in[13]; p.bs[0] = (const float*)d_in[14];
  p.W[1]  = (const float*)d_in[15]; p.bs[1] = (const float*)d_in[16];
  p.W[2]  = (const float*)d_in[17]; p.bs[2] = (const float*)d_in[18];
  p.W4    = (const float*)d_in[19]; p.b4    = (const float*)d_in[20];
  p.out   = (float*)d_out;

  float* ws   = (float*)d_ws;
  p.wt3       = ws;                          // 3*69632 = 208896 floats
  p.partials  = ws + 208896;                 // 4*2*6*64 = 3072
  p.flags     = (unsigned*)(ws + 211968);    // 1024 uints
  p.sbuf      = ws + 212992;                 // 2*2*2048*256 = 2,097,152 floats
  p.xT        = ws + 2310144;                // 50*524288 = 26,214,400 floats
  size_t need = ((size_t)2310144 + (size_t)TT * BB * SS) * sizeof(float);
  p.use_xt    = (ws_size >= need) ? 1 : 0;

  hipMemsetAsync((void*)p.flags, 0, 4096, stream);
  snn_pipe<<<dim3(NGRID), dim3(NTHR), 0, stream>>>(p);
}